// Round 19
// baseline (171.260 us; speedup 1.0000x reference)
//
#include <hip/hip_runtime.h>
#include <hip/hip_bf16.h>
#include <cstdint>
#include <cstddef>

#define NQ      14
#define SDIM    16384          // 1 << NQ
#define NGATES  39             // 3 layers * 13 sparse two-qubit chain gates
#define NBATCH  1024
#define KSPLIT  16
#define GENT    42             // 39 chain gates + 3 per-layer U0

typedef short bf16x8 __attribute__((ext_vector_type(8)));
typedef float f32x4  __attribute__((ext_vector_type(4)));
typedef __fp16 half2v __attribute__((ext_vector_type(2)));

// ---------------------------------------------------------------------------
// scalar complex helpers (prep kernel only)
// ---------------------------------------------------------------------------
__device__ __forceinline__ float2 cmul(float2 a, float2 b) {
    return make_float2(fmaf(a.x, b.x, -a.y * b.y), fmaf(a.x, b.y, a.y * b.x));
}
__device__ __forceinline__ void cfma(float2 &o, float2 a, float2 b) {
    o.x = fmaf(a.x, b.x, fmaf(-a.y, b.y, o.x));
    o.y = fmaf(a.x, b.y, fmaf( a.y, b.x, o.y));
}

// ---------------------------------------------------------------------------
// Packed fp16 complex helpers (r16/r18-verified). Amp = one uint (lo=re,
// hi=im). Coefficients bound as SGPR ("s") — wave-uniform, rides the scalar
// file, keeps VGPR demand at the 32-reg clamp with zero spill.
// ---------------------------------------------------------------------------
__device__ __forceinline__ unsigned cmul16(unsigned c, unsigned a) {
    unsigned t, o;
    asm("v_pk_mul_f16 %0, %2, %3 op_sel:[0,0] op_sel_hi:[0,1]\n\t"
        "v_pk_fma_f16 %1, %2, %3, %0 op_sel:[1,1,0] op_sel_hi:[1,0,1] neg_lo:[1,0,0]"
        : "=&v"(t), "=v"(o) : "s"(c), "v"(a));
    return o;
}
__device__ __forceinline__ void cfma16(unsigned &o, unsigned c, unsigned a) {
    unsigned t;
    asm("v_pk_fma_f16 %0, %2, %3, %1 op_sel:[0,0,0] op_sel_hi:[0,1,1]\n\t"
        "v_pk_fma_f16 %1, %2, %3, %0 op_sel:[1,1,0] op_sel_hi:[1,0,1] neg_lo:[1,0,0]"
        : "=&v"(t), "+v"(o) : "s"(c), "v"(a));
}

__device__ void mm2(const float2 A[2][2], const float2 B[2][2], float2 C[2][2]) {
    #pragma unroll
    for (int i = 0; i < 2; ++i)
        #pragma unroll
        for (int j = 0; j < 2; ++j) {
            float2 t = cmul(A[i][0], B[0][j]);
            cfma(t, A[i][1], B[1][j]);
            C[i][j] = t;
        }
}

// U = RZ(g) * RY(b) * RX(a)  (optionally right-multiplied by encoding RY for layer 0)
__device__ void build_u(const float* __restrict__ rp, const float* __restrict__ enc,
                        int l, int q, float2 U[2][2]) {
    const float* p = rp + (l * NQ + q) * 3;
    float ha = 0.5f * p[0], hb = 0.5f * p[1], hg = 0.5f * p[2];
    float cx = cosf(ha), sx = sinf(ha);
    float cy = cosf(hb), sy = sinf(hb);
    float cz = cosf(hg), sz = sinf(hg);
    float2 RX[2][2] = { { make_float2(cx, 0.f), make_float2(0.f, -sx) },
                        { make_float2(0.f, -sx), make_float2(cx, 0.f) } };
    float2 RY[2][2] = { { make_float2(cy, 0.f), make_float2(-sy, 0.f) },
                        { make_float2(sy, 0.f), make_float2(cy, 0.f) } };
    float2 W[2][2];
    mm2(RY, RX, W);
    float2 zl = make_float2(cz, -sz), zh = make_float2(cz, sz);
    float2 V[2][2];
    V[0][0] = cmul(zl, W[0][0]); V[0][1] = cmul(zl, W[0][1]);
    V[1][0] = cmul(zh, W[1][0]); V[1][1] = cmul(zh, W[1][1]);
    if (l == 0) {   // encoding RY applied BEFORE layer-0 rotations -> right-multiply
        float he = 0.5f * enc[q];
        float ce = cosf(he), se = sinf(he);
        float2 RE[2][2] = { { make_float2(ce, 0.f), make_float2(-se, 0.f) },
                            { make_float2(se, 0.f), make_float2(ce, 0.f) } };
        mm2(V, RE, U);
    } else {
        U[0][0] = V[0][0]; U[0][1] = V[0][1];
        U[1][0] = V[1][0]; U[1][1] = V[1][1];
    }
}

__device__ __forceinline__ unsigned pkh(float2 f) {
    half2v h = __builtin_amdgcn_cvt_pkrtz(f.x, f.y);
    return *(unsigned*)&h;
}

// ---------------------------------------------------------------------------
// Kernel 0: per-batch gate-table build (gates only — the 96 MB w1-transpose
// pass is gone; transpose+convert now happens inside gemm1's staging).
// gtab[b]: entries 0..38 = chain gates (8 uints); 39..41 = per-layer U(q0).
// ---------------------------------------------------------------------------
__global__ __launch_bounds__(64) void prep_kernel(
    const float* __restrict__ x,     // (1024, 64)
    const float* __restrict__ ep,    // (64, 14)
    const float* __restrict__ rp,    // (3, 14, 3)
    const float* __restrict__ ent,   // (3, 13)
    unsigned* __restrict__ gtab)     // (1024, 42*8)
{
    __shared__ float angles[NQ];
    const int b = blockIdx.x, t = threadIdx.x;

    if (t < NQ) {
        float a = 0.f;
        const float* xr = x + (size_t)b * 64;
        #pragma unroll 8
        for (int k = 0; k < 64; ++k) a = fmaf(xr[k], ep[k * NQ + t], a);
        angles[t] = a;
    }
    __syncthreads();

    unsigned* G0 = gtab + (size_t)b * (GENT * 8);
    if (t < NGATES) {
        int l = t / 13, jj = t - l * 13;     // gate on qubits (jj, jj+1)
        float2 Ut[2][2];
        build_u(rp, angles, l, jj + 1, Ut);
        float th = ent[l * 13 + jj];
        float ct = cosf(th), s = sinf(th);
        unsigned* G = G0 + t * 8;
        G[0] = pkh(Ut[0][0]); G[1] = pkh(Ut[0][1]); G[2] = pkh(Ut[1][0]); G[3] = pkh(Ut[1][1]);
        G[4] = pkh(make_float2(fmaf(ct, Ut[0][0].x, -s * Ut[1][0].y), fmaf(ct, Ut[0][0].y, s * Ut[1][0].x)));
        G[5] = pkh(make_float2(fmaf(ct, Ut[0][1].x, -s * Ut[1][1].y), fmaf(ct, Ut[0][1].y, s * Ut[1][1].x)));
        G[6] = pkh(make_float2(fmaf(ct, Ut[1][0].x, -s * Ut[0][0].y), fmaf(ct, Ut[1][0].y, s * Ut[0][0].x)));
        G[7] = pkh(make_float2(fmaf(ct, Ut[1][1].x, -s * Ut[0][1].y), fmaf(ct, Ut[1][1].y, s * Ut[0][1].x)));
    } else if (t < GENT) {
        int l = t - NGATES;
        float2 U[2][2];
        build_u(rp, angles, l, 0, U);
        unsigned* D = G0 + t * 8;
        D[0] = pkh(U[0][0]); D[1] = pkh(U[0][1]); D[2] = pkh(U[1][0]); D[3] = pkh(U[1][1]);
    }
}

// ---------------------------------------------------------------------------
// Sparse chain-gate on the 4-qubit register window — fp16-packed, SGPR coeffs.
// ---------------------------------------------------------------------------
template<int CP>
__device__ __forceinline__ void gate_sparse8(unsigned v[16], const unsigned* __restrict__ G) {
    {
        unsigned c00 = G[0], c01 = G[1], c10 = G[2], c11 = G[3];
        #pragma unroll
        for (int rr = 0; rr < 4; ++rr) {
            const int base = ((rr >> CP) << (CP + 2)) | (rr & ((1 << CP) - 1));
            const int m0 = base, m2 = base | (2 << CP);
            unsigned a0 = v[m0], a2 = v[m2];
            unsigned o0 = cmul16(c00, a0); cfma16(o0, c01, a2);
            unsigned o2 = cmul16(c10, a0); cfma16(o2, c11, a2);
            v[m0] = o0; v[m2] = o2;
        }
    }
    {
        unsigned c00 = G[4], c01 = G[5], c10 = G[6], c11 = G[7];
        #pragma unroll
        for (int rr = 0; rr < 4; ++rr) {
            const int base = ((rr >> CP) << (CP + 2)) | (rr & ((1 << CP) - 1));
            const int m1 = base | (1 << CP), m3 = base | (3 << CP);
            unsigned a1 = v[m1], a3 = v[m3];
            unsigned o1 = cmul16(c00, a1); cfma16(o1, c01, a3);
            unsigned o3 = cmul16(c10, a1); cfma16(o3, c11, a3);
            v[m1] = o1; v[m3] = o3;
        }
    }
}

// ---------------------------------------------------------------------------
// LDS layout (b32): slot = amp ^ ((amp>>5)&31); bank = slot[4:0]. All five
// mappings give exactly 2 lanes/bank (free) per wave64 b32 access.
// ---------------------------------------------------------------------------
template<int P> __device__ __forceinline__ int pass_i0(int tid) {
    if constexpr (P == 0) return ((tid & 15) << 5) | (tid & 16) | ((tid & 32) << 4) | ((tid & 0x3C0) << 4);
    if constexpr (P == 1) return (tid & 7) | (((tid >> 4) & 1) << 7) | (((tid >> 3) & 1) << 8)
                               | (((tid >> 5) & 1) << 9) | ((tid >> 6) << 10);
    if constexpr (P == 2) return (tid & 63) | ((tid >> 6) << 10);
    if constexpr (P == 3) return (tid & 31) | (((tid >> 6) & 15) << 5) | (((tid >> 5) & 1) << 13);
    if constexpr (P == 4) return (tid & 31) | (((tid >> 6) & 15) << 5) | (((tid >> 5) & 1) << 9);
    return 0;
}
template<int P> __device__ __forceinline__ constexpr int pass_cj(int j) {
    if constexpr (P == 0) return j * 4;
    if constexpr (P == 1) return (((j << 3) | (j >> 2))) * 4;
    if constexpr (P == 2) return (((j << 6) | (j << 1))) * 4;
    if constexpr (P == 3) return (((j << 9) | ((j & 1) << 4))) * 4;
    if constexpr (P == 4) return (j << 10) * 4;
    return 0;
}

template<int P, bool INIT, bool U0F, bool EMIT>
__device__ __forceinline__ void passT(char* __restrict__ smemc,
                                      const unsigned* __restrict__ gb,
                                      const unsigned* __restrict__ u0,
                                      __hip_bfloat16* __restrict__ fr, int tid) {
    const int i0   = pass_i0<P>(tid);
    const int base = (i0 ^ ((i0 >> 5) & 31)) * 4;

    unsigned v[16];
    if (INIT) {
        #pragma unroll
        for (int j = 0; j < 16; ++j) v[j] = 0u;
        if (tid == 0) v[0] = 0x3C00u;       // fp16 (1.0, 0.0)
    } else {
        #pragma unroll
        for (int j = 0; j < 16; ++j)
            v[j] = *(const unsigned*)(smemc + (base ^ pass_cj<P>(j)));
    }

    if (U0F) {
        unsigned u00 = u0[0], u01 = u0[1], u10 = u0[2], u11 = u0[3];
        #pragma unroll
        for (int k = 0; k < 8; ++k) {
            unsigned e = v[2 * k], o = v[2 * k + 1];
            unsigned ne = cmul16(u00, e); cfma16(ne, u01, o);
            unsigned no = cmul16(u10, e); cfma16(no, u11, o);
            v[2 * k] = ne; v[2 * k + 1] = no;
        }
    }

    if (P < 4) {
        gate_sparse8<0>(v, gb);
        gate_sparse8<1>(v, gb + 8);
        gate_sparse8<2>(v, gb + 16);
    } else {
        gate_sparse8<2>(v, gb);
    }

    if (EMIT) {
        #pragma unroll
        for (int j = 0; j < 16; ++j) {
            half2v h = *(half2v*)&v[j];
            float re = (float)h.x, im = (float)h.y;
            fr[i0 + (j << 10)] = __float2bfloat16(fmaf(re, re, im * im));
        }
    } else {
        #pragma unroll
        for (int j = 0; j < 16; ++j)
            *(unsigned*)(smemc + (base ^ pass_cj<P>(j))) = v[j];
    }
}

// ---------------------------------------------------------------------------
// Kernel 1: circuit simulation (r18-verified: fp16-packed, SGPR coeffs,
// 64 KiB LDS, waves_per_eu(8,8) -> 2 blocks/CU, VGPR 32, ~74% occupancy).
// ---------------------------------------------------------------------------
__global__ __launch_bounds__(1024) __attribute__((amdgpu_waves_per_eu(8, 8)))
void sim_kernel(
    const unsigned* __restrict__ gtab,   // (1024, 42*8) packed fp16 coeffs
    __hip_bfloat16* __restrict__ feats)  // (1024, 16384) bf16
{
    __shared__ unsigned int st[SDIM];      // 65536 B exactly

    char* smemc = (char*)st;
    const int tid = threadIdx.x;
    const int b   = blockIdx.x;

    const unsigned* gt = gtab + (size_t)b * (GENT * 8);
    __hip_bfloat16* fr = feats + (size_t)b * SDIM;

    {
        const unsigned* gl = gt;
        passT<0, true,  true,  false>(smemc, gl,          gt + 39 * 8, nullptr, tid); __syncthreads();
        passT<1, false, false, false>(smemc, gl + 3 * 8,  nullptr,     nullptr, tid); __syncthreads();
        passT<2, false, false, false>(smemc, gl + 6 * 8,  nullptr,     nullptr, tid); __syncthreads();
        passT<3, false, false, false>(smemc, gl + 9 * 8,  nullptr,     nullptr, tid); __syncthreads();
        passT<4, false, false, false>(smemc, gl + 12 * 8, nullptr,     nullptr, tid); __syncthreads();
    }
    {
        const unsigned* gl = gt + 13 * 8;
        passT<0, false, true,  false>(smemc, gl,          gt + 40 * 8, nullptr, tid); __syncthreads();
        passT<1, false, false, false>(smemc, gl + 3 * 8,  nullptr,     nullptr, tid); __syncthreads();
        passT<2, false, false, false>(smemc, gl + 6 * 8,  nullptr,     nullptr, tid); __syncthreads();
        passT<3, false, false, false>(smemc, gl + 9 * 8,  nullptr,     nullptr, tid); __syncthreads();
        passT<4, false, false, false>(smemc, gl + 12 * 8, nullptr,     nullptr, tid); __syncthreads();
    }
    {
        const unsigned* gl = gt + 26 * 8;
        passT<0, false, true,  false>(smemc, gl,          gt + 41 * 8, nullptr, tid); __syncthreads();
        passT<1, false, false, false>(smemc, gl + 3 * 8,  nullptr,     nullptr, tid); __syncthreads();
        passT<2, false, false, false>(smemc, gl + 6 * 8,  nullptr,     nullptr, tid); __syncthreads();
        passT<3, false, false, false>(smemc, gl + 9 * 8,  nullptr,     nullptr, tid); __syncthreads();
        passT<4, false, false, true >(smemc, gl + 12 * 8, nullptr,     fr,      tid);
    }
}

// ---------------------------------------------------------------------------
// Kernel 2: MFMA GEMM1 v2 — 512 threads (8 waves = 2/SIMD, vs r9's 1/SIMD)
// and B staged DIRECTLY from w1 fp32 (register transpose: 8 strided dword
// loads + bf16 pack per 16B chunk; w1 = 16 MB, L3-resident). Same verified
// chunk-swizzle: physical chunk p at row r holds logical kb = p^((r>>1)&3).
// Wave w: output rows (w>>1)*32, cols (w&1)*64; 2x4 frags of 16x16x32.
// ---------------------------------------------------------------------------
__global__ __launch_bounds__(512) void gemm1_mfma(
    const __hip_bfloat16* __restrict__ A,   // feats (1024, 16384) bf16
    const float* __restrict__ W1,           // w1 (16384, 256) fp32
    float* __restrict__ part)               // (16, 1024, 256)
{
    __shared__ char As[8192];
    __shared__ char Bs[8192];
    const int tid  = threadIdx.x;
    const int lane = tid & 63;
    const int wave = tid >> 6;
    const int wm = wave >> 1, wn = wave & 1;
    const int bm = blockIdx.x, bn = blockIdx.y, ks = blockIdx.z;
    const int k0 = ks * 1024;

    // A chunk (1/thread): row ra_, logical k-chunk kba
    const int ra_ = tid >> 2, kba = (tid & 3) ^ ((ra_ >> 1) & 3);
    const __hip_bfloat16* Ap = A + (size_t)(bm * 128 + ra_) * SDIM + k0 + kba * 8;
    // B chunk (1/thread): col nb_, logical k-chunk kbb; 8 fp32 rows of w1
    const int nb_ = tid >> 2, kbb = (tid & 3) ^ ((nb_ >> 1) & 3);
    const float* Bp = W1 + (size_t)(k0 + kbb * 8) * 256 + bn * 128 + nb_;

    const int kbx  = lane >> 4;
    const int arow = wm * 32 + (lane & 15);
    const int brow = wn * 64 + (lane & 15);
    const int abase = arow * 64 + ((kbx ^ ((arow >> 1) & 3)) << 4);
    const int bbase = brow * 64 + ((kbx ^ ((brow >> 1) & 3)) << 4);

    f32x4 acc[2][4];
    #pragma unroll
    for (int i = 0; i < 2; ++i)
        #pragma unroll
        for (int j = 0; j < 4; ++j)
            acc[i][j] = (f32x4){0.f, 0.f, 0.f, 0.f};

    uint4 ra = *(const uint4*)Ap;
    float rb[8];
    #pragma unroll
    for (int j = 0; j < 8; ++j) rb[j] = Bp[(size_t)j * 256];

    for (int kt = 0; kt < 32; ++kt) {
        uint4 bw;   // pack 8 fp32 -> 8 bf16 (same RN conversion as old wtr)
        {
            unsigned u[4];
            #pragma unroll
            for (int i = 0; i < 4; ++i) {
                __hip_bfloat16 h0 = __float2bfloat16(rb[2 * i]);
                __hip_bfloat16 h1 = __float2bfloat16(rb[2 * i + 1]);
                u[i] = (unsigned)*(unsigned short*)&h0 | ((unsigned)*(unsigned short*)&h1 << 16);
            }
            bw = make_uint4(u[0], u[1], u[2], u[3]);
        }
        *(uint4*)(As + tid * 16) = ra;
        *(uint4*)(Bs + tid * 16) = bw;
        __syncthreads();
        if (kt < 31) {   // prefetch next K-step while MFMAs run
            const int d = (kt + 1) * 32;
            ra = *(const uint4*)(Ap + d);
            #pragma unroll
            for (int j = 0; j < 8; ++j) rb[j] = Bp[((size_t)d + j) * 256];
        }
        bf16x8 a[2], b[4];
        #pragma unroll
        for (int mi = 0; mi < 2; ++mi) a[mi] = *(const bf16x8*)(As + abase + mi * 1024);
        #pragma unroll
        for (int ni = 0; ni < 4; ++ni) b[ni] = *(const bf16x8*)(Bs + bbase + ni * 1024);
        #pragma unroll
        for (int mi = 0; mi < 2; ++mi)
            #pragma unroll
            for (int ni = 0; ni < 4; ++ni)
                acc[mi][ni] = __builtin_amdgcn_mfma_f32_16x16x32_bf16(a[mi], b[ni], acc[mi][ni], 0, 0, 0);
        __syncthreads();
    }

    float* P = part + ((size_t)ks * NBATCH + bm * 128 + wm * 32) * 256 + bn * 128 + wn * 64;
    const int mrow = (lane >> 4) * 4;
    const int ncol = lane & 15;
    #pragma unroll
    for (int mi = 0; mi < 2; ++mi)
        #pragma unroll
        for (int ni = 0; ni < 4; ++ni) {
            #pragma unroll
            for (int r = 0; r < 4; ++r)
                P[(size_t)(mi * 16 + mrow + r) * 256 + ni * 16 + ncol] = acc[mi][ni][r];
        }
}

// ---------------------------------------------------------------------------
// Kernel 3: reduce split-K partials + bias + relu, then the two small GEMMs.
// ---------------------------------------------------------------------------
__global__ __launch_bounds__(256) void tail_kernel(
    const float* __restrict__ part,  // (16, 1024, 256)
    const float* __restrict__ b1,
    const float* __restrict__ w2,    // (256, 128)
    const float* __restrict__ b2,
    const float* __restrict__ w3,    // (128, 64)
    const float* __restrict__ b3,
    float* __restrict__ out)         // (1024, 64)
{
    __shared__ float h1[256];
    __shared__ float h2[128];
    const int b = blockIdx.x, t = threadIdx.x;

    float s = b1[t];
    #pragma unroll
    for (int sp = 0; sp < KSPLIT; ++sp)
        s += part[((size_t)sp * NBATCH + b) * 256 + t];
    h1[t] = fmaxf(s, 0.f);
    __syncthreads();

    if (t < 128) {
        float acc = b2[t];
        #pragma unroll 4
        for (int k = 0; k < 256; ++k) acc = fmaf(h1[k], w2[k * 128 + t], acc);
        h2[t] = fmaxf(acc, 0.f);
    }
    __syncthreads();

    if (t < 64) {
        float acc = b3[t];
        #pragma unroll 4
        for (int k = 0; k < 128; ++k) acc = fmaf(h2[k], w3[k * 64 + t], acc);
        out[(size_t)b * 64 + t] = acc;
    }
}

// ---------------------------------------------------------------------------
extern "C" void kernel_launch(void* const* d_in, const int* in_sizes, int n_in,
                              void* d_out, int out_size, void* d_ws, size_t ws_size,
                              hipStream_t stream) {
    const float* x   = (const float*)d_in[0];
    const float* ep  = (const float*)d_in[1];
    const float* rp  = (const float*)d_in[2];
    const float* ent = (const float*)d_in[3];
    const float* w1  = (const float*)d_in[4];
    const float* b1  = (const float*)d_in[5];
    const float* w2  = (const float*)d_in[6];
    const float* b2  = (const float*)d_in[7];
    const float* w3  = (const float*)d_in[8];
    const float* b3  = (const float*)d_in[9];
    float* out = (float*)d_out;

    // ws: feats bf16 (32 MiB) | part fp32 (16 MiB) | gtab (1.4 MiB)
    __hip_bfloat16* feats = (__hip_bfloat16*)d_ws;
    float*          part  = (float*)(feats + (size_t)NBATCH * SDIM);
    unsigned*       gtab  = (unsigned*)(part + (size_t)KSPLIT * NBATCH * 256);

    prep_kernel<<<NBATCH, 64, 0, stream>>>(x, ep, rp, ent, gtab);
    sim_kernel<<<NBATCH, 1024, 0, stream>>>(gtab, feats);
    gemm1_mfma<<<dim3(8, 2, KSPLIT), 512, 0, stream>>>(feats, w1, part);
    tail_kernel<<<NBATCH, 256, 0, stream>>>(part, b1, w2, b2, w3, b3, out);
}

// Round 20
// 156.983 us; speedup vs baseline: 1.0909x; 1.0909x over previous
//
#include <hip/hip_runtime.h>
#include <hip/hip_bf16.h>
#include <cstdint>
#include <cstddef>

#define NQ      14
#define SDIM    16384          // 1 << NQ
#define NGATES  39             // 3 layers * 13 sparse two-qubit chain gates
#define NBATCH  1024
#define KSPLIT  16
#define GENT    42             // 39 chain gates + 3 per-layer U0

typedef short bf16x8 __attribute__((ext_vector_type(8)));
typedef float f32x4  __attribute__((ext_vector_type(4)));
typedef __fp16 half2v __attribute__((ext_vector_type(2)));

// ---------------------------------------------------------------------------
// scalar complex helpers (prep path only)
// ---------------------------------------------------------------------------
__device__ __forceinline__ float2 cmul(float2 a, float2 b) {
    return make_float2(fmaf(a.x, b.x, -a.y * b.y), fmaf(a.x, b.y, a.y * b.x));
}
__device__ __forceinline__ void cfma(float2 &o, float2 a, float2 b) {
    o.x = fmaf(a.x, b.x, fmaf(-a.y, b.y, o.x));
    o.y = fmaf(a.x, b.y, fmaf( a.y, b.x, o.y));
}

// ---------------------------------------------------------------------------
// Packed fp16 complex helpers (r16/r18-verified). Amp = one uint (lo=re,
// hi=im). Coefficients bound as SGPR ("s") — wave-uniform, rides the scalar
// file, keeps VGPR demand at the 32-reg clamp with zero spill.
// ---------------------------------------------------------------------------
__device__ __forceinline__ unsigned cmul16(unsigned c, unsigned a) {
    unsigned t, o;
    asm("v_pk_mul_f16 %0, %2, %3 op_sel:[0,0] op_sel_hi:[0,1]\n\t"
        "v_pk_fma_f16 %1, %2, %3, %0 op_sel:[1,1,0] op_sel_hi:[1,0,1] neg_lo:[1,0,0]"
        : "=&v"(t), "=v"(o) : "s"(c), "v"(a));
    return o;
}
__device__ __forceinline__ void cfma16(unsigned &o, unsigned c, unsigned a) {
    unsigned t;
    asm("v_pk_fma_f16 %0, %2, %3, %1 op_sel:[0,0,0] op_sel_hi:[0,1,1]\n\t"
        "v_pk_fma_f16 %1, %2, %3, %0 op_sel:[1,1,0] op_sel_hi:[1,0,1] neg_lo:[1,0,0]"
        : "=&v"(t), "+v"(o) : "s"(c), "v"(a));
}

__device__ void mm2(const float2 A[2][2], const float2 B[2][2], float2 C[2][2]) {
    #pragma unroll
    for (int i = 0; i < 2; ++i)
        #pragma unroll
        for (int j = 0; j < 2; ++j) {
            float2 t = cmul(A[i][0], B[0][j]);
            cfma(t, A[i][1], B[1][j]);
            C[i][j] = t;
        }
}

// U = RZ(g) * RY(b) * RX(a)  (optionally right-multiplied by encoding RY for layer 0)
__device__ void build_u(const float* __restrict__ rp, const float* __restrict__ enc,
                        int l, int q, float2 U[2][2]) {
    const float* p = rp + (l * NQ + q) * 3;
    float ha = 0.5f * p[0], hb = 0.5f * p[1], hg = 0.5f * p[2];
    float cx = cosf(ha), sx = sinf(ha);
    float cy = cosf(hb), sy = sinf(hb);
    float cz = cosf(hg), sz = sinf(hg);
    float2 RX[2][2] = { { make_float2(cx, 0.f), make_float2(0.f, -sx) },
                        { make_float2(0.f, -sx), make_float2(cx, 0.f) } };
    float2 RY[2][2] = { { make_float2(cy, 0.f), make_float2(-sy, 0.f) },
                        { make_float2(sy, 0.f), make_float2(cy, 0.f) } };
    float2 W[2][2];
    mm2(RY, RX, W);
    float2 zl = make_float2(cz, -sz), zh = make_float2(cz, sz);
    float2 V[2][2];
    V[0][0] = cmul(zl, W[0][0]); V[0][1] = cmul(zl, W[0][1]);
    V[1][0] = cmul(zh, W[1][0]); V[1][1] = cmul(zh, W[1][1]);
    if (l == 0) {   // encoding RY applied BEFORE layer-0 rotations -> right-multiply
        float he = 0.5f * enc[q];
        float ce = cosf(he), se = sinf(he);
        float2 RE[2][2] = { { make_float2(ce, 0.f), make_float2(-se, 0.f) },
                            { make_float2(se, 0.f), make_float2(ce, 0.f) } };
        mm2(V, RE, U);
    } else {
        U[0][0] = V[0][0]; U[0][1] = V[0][1];
        U[1][0] = V[1][0]; U[1][1] = V[1][1];
    }
}

__device__ __forceinline__ unsigned pkh(float2 f) {
    half2v h = __builtin_amdgcn_cvt_pkrtz(f.x, f.y);
    return *(unsigned*)&h;
}

// ---------------------------------------------------------------------------
// Kernel 0 (merged, r18-verified): per-batch gate-table build + w1
// transpose/convert. Block b: batch b's gates AND w1 tile (kb=b>>2, nb=b&3).
// gtab[b]: entries 0..38 = chain gates (8 uints); 39..41 = per-layer U(q0).
// ---------------------------------------------------------------------------
__global__ __launch_bounds__(256) void prep_wtr_kernel(
    const float* __restrict__ x,     // (1024, 64)
    const float* __restrict__ ep,    // (64, 14)
    const float* __restrict__ rp,    // (3, 14, 3)
    const float* __restrict__ ent,   // (3, 13)
    const float* __restrict__ w1,    // (16384, 256)
    unsigned* __restrict__ gtab,     // (1024, 42*8)
    __hip_bfloat16* __restrict__ w1t) // (256, 16384)
{
    __shared__ float tile[64][65];
    __shared__ float angles[NQ];
    const int b = blockIdx.x, t = threadIdx.x;
    const int kb = (b >> 2) * 64, nb = (b & 3) * 64;

    // stage w1 tile
    #pragma unroll
    for (int i = 0; i < 16; ++i) {
        int idx = t + i * 256; int r = idx >> 6, c = idx & 63;
        tile[r][c] = w1[(size_t)(kb + r) * 256 + nb + c];
    }
    // encoding angles for batch b
    if (t < NQ) {
        float a = 0.f;
        const float* xr = x + (size_t)b * 64;
        #pragma unroll 8
        for (int k = 0; k < 64; ++k) a = fmaf(xr[k], ep[k * NQ + t], a);
        angles[t] = a;
    }
    __syncthreads();

    // transposed bf16 write
    #pragma unroll
    for (int i = 0; i < 16; ++i) {
        int idx = t + i * 256; int n = idx >> 6, k = idx & 63;
        w1t[(size_t)(nb + n) * SDIM + kb + k] = __float2bfloat16(tile[k][n]);
    }

    // gate tables
    unsigned* G0 = gtab + (size_t)b * (GENT * 8);
    if (t < NGATES) {
        int l = t / 13, jj = t - l * 13;     // gate on qubits (jj, jj+1)
        float2 Ut[2][2];
        build_u(rp, angles, l, jj + 1, Ut);
        float th = ent[l * 13 + jj];
        float ct = cosf(th), s = sinf(th);
        unsigned* G = G0 + t * 8;
        G[0] = pkh(Ut[0][0]); G[1] = pkh(Ut[0][1]); G[2] = pkh(Ut[1][0]); G[3] = pkh(Ut[1][1]);
        G[4] = pkh(make_float2(fmaf(ct, Ut[0][0].x, -s * Ut[1][0].y), fmaf(ct, Ut[0][0].y, s * Ut[1][0].x)));
        G[5] = pkh(make_float2(fmaf(ct, Ut[0][1].x, -s * Ut[1][1].y), fmaf(ct, Ut[0][1].y, s * Ut[1][1].x)));
        G[6] = pkh(make_float2(fmaf(ct, Ut[1][0].x, -s * Ut[0][0].y), fmaf(ct, Ut[1][0].y, s * Ut[0][0].x)));
        G[7] = pkh(make_float2(fmaf(ct, Ut[1][1].x, -s * Ut[0][1].y), fmaf(ct, Ut[1][1].y, s * Ut[0][1].x)));
    } else if (t < GENT) {
        int l = t - NGATES;
        float2 U[2][2];
        build_u(rp, angles, l, 0, U);
        unsigned* D = G0 + t * 8;
        D[0] = pkh(U[0][0]); D[1] = pkh(U[0][1]); D[2] = pkh(U[1][0]); D[3] = pkh(U[1][1]);
    }
}

// ---------------------------------------------------------------------------
// Sparse chain-gate on the 4-qubit register window — fp16-packed, SGPR coeffs.
// ---------------------------------------------------------------------------
template<int CP>
__device__ __forceinline__ void gate_sparse8(unsigned v[16], const unsigned* __restrict__ G) {
    {
        unsigned c00 = G[0], c01 = G[1], c10 = G[2], c11 = G[3];
        #pragma unroll
        for (int rr = 0; rr < 4; ++rr) {
            const int base = ((rr >> CP) << (CP + 2)) | (rr & ((1 << CP) - 1));
            const int m0 = base, m2 = base | (2 << CP);
            unsigned a0 = v[m0], a2 = v[m2];
            unsigned o0 = cmul16(c00, a0); cfma16(o0, c01, a2);
            unsigned o2 = cmul16(c10, a0); cfma16(o2, c11, a2);
            v[m0] = o0; v[m2] = o2;
        }
    }
    {
        unsigned c00 = G[4], c01 = G[5], c10 = G[6], c11 = G[7];
        #pragma unroll
        for (int rr = 0; rr < 4; ++rr) {
            const int base = ((rr >> CP) << (CP + 2)) | (rr & ((1 << CP) - 1));
            const int m1 = base | (1 << CP), m3 = base | (3 << CP);
            unsigned a1 = v[m1], a3 = v[m3];
            unsigned o1 = cmul16(c00, a1); cfma16(o1, c01, a3);
            unsigned o3 = cmul16(c10, a1); cfma16(o3, c11, a3);
            v[m1] = o1; v[m3] = o3;
        }
    }
}

// ---------------------------------------------------------------------------
// LDS layout (b32): slot = amp ^ ((amp>>5)&31); bank = slot[4:0]. All five
// mappings give exactly 2 lanes/bank (free) per wave64 b32 access.
// ---------------------------------------------------------------------------
template<int P> __device__ __forceinline__ int pass_i0(int tid) {
    if constexpr (P == 0) return ((tid & 15) << 5) | (tid & 16) | ((tid & 32) << 4) | ((tid & 0x3C0) << 4);
    if constexpr (P == 1) return (tid & 7) | (((tid >> 4) & 1) << 7) | (((tid >> 3) & 1) << 8)
                               | (((tid >> 5) & 1) << 9) | ((tid >> 6) << 10);
    if constexpr (P == 2) return (tid & 63) | ((tid >> 6) << 10);
    if constexpr (P == 3) return (tid & 31) | (((tid >> 6) & 15) << 5) | (((tid >> 5) & 1) << 13);
    if constexpr (P == 4) return (tid & 31) | (((tid >> 6) & 15) << 5) | (((tid >> 5) & 1) << 9);
    return 0;
}
template<int P> __device__ __forceinline__ constexpr int pass_cj(int j) {
    if constexpr (P == 0) return j * 4;
    if constexpr (P == 1) return (((j << 3) | (j >> 2))) * 4;
    if constexpr (P == 2) return (((j << 6) | (j << 1))) * 4;
    if constexpr (P == 3) return (((j << 9) | ((j & 1) << 4))) * 4;
    if constexpr (P == 4) return (j << 10) * 4;
    return 0;
}

template<int P, bool INIT, bool U0F, bool EMIT>
__device__ __forceinline__ void passT(char* __restrict__ smemc,
                                      const unsigned* __restrict__ gb,
                                      const unsigned* __restrict__ u0,
                                      __hip_bfloat16* __restrict__ fr, int tid) {
    const int i0   = pass_i0<P>(tid);
    const int base = (i0 ^ ((i0 >> 5) & 31)) * 4;

    unsigned v[16];
    if (INIT) {
        #pragma unroll
        for (int j = 0; j < 16; ++j) v[j] = 0u;
        if (tid == 0) v[0] = 0x3C00u;       // fp16 (1.0, 0.0)
    } else {
        #pragma unroll
        for (int j = 0; j < 16; ++j)
            v[j] = *(const unsigned*)(smemc + (base ^ pass_cj<P>(j)));
    }

    if (U0F) {
        unsigned u00 = u0[0], u01 = u0[1], u10 = u0[2], u11 = u0[3];
        #pragma unroll
        for (int k = 0; k < 8; ++k) {
            unsigned e = v[2 * k], o = v[2 * k + 1];
            unsigned ne = cmul16(u00, e); cfma16(ne, u01, o);
            unsigned no = cmul16(u10, e); cfma16(no, u11, o);
            v[2 * k] = ne; v[2 * k + 1] = no;
        }
    }

    if (P < 4) {
        gate_sparse8<0>(v, gb);
        gate_sparse8<1>(v, gb + 8);
        gate_sparse8<2>(v, gb + 16);
    } else {
        gate_sparse8<2>(v, gb);
    }

    if (EMIT) {
        #pragma unroll
        for (int j = 0; j < 16; ++j) {
            half2v h = *(half2v*)&v[j];
            float re = (float)h.x, im = (float)h.y;
            fr[i0 + (j << 10)] = __float2bfloat16(fmaf(re, re, im * im));
        }
    } else {
        #pragma unroll
        for (int j = 0; j < 16; ++j)
            *(unsigned*)(smemc + (base ^ pass_cj<P>(j))) = v[j];
    }
}

// ---------------------------------------------------------------------------
// Kernel 1: circuit simulation (r18-verified: fp16-packed, SGPR coeffs,
// 64 KiB LDS, waves_per_eu(8,8) -> 2 blocks/CU, VGPR 32, ~74% occupancy).
// ---------------------------------------------------------------------------
__global__ __launch_bounds__(1024) __attribute__((amdgpu_waves_per_eu(8, 8)))
void sim_kernel(
    const unsigned* __restrict__ gtab,   // (1024, 42*8) packed fp16 coeffs
    __hip_bfloat16* __restrict__ feats)  // (1024, 16384) bf16
{
    __shared__ unsigned int st[SDIM];      // 65536 B exactly

    char* smemc = (char*)st;
    const int tid = threadIdx.x;
    const int b   = blockIdx.x;

    const unsigned* gt = gtab + (size_t)b * (GENT * 8);
    __hip_bfloat16* fr = feats + (size_t)b * SDIM;

    {
        const unsigned* gl = gt;
        passT<0, true,  true,  false>(smemc, gl,          gt + 39 * 8, nullptr, tid); __syncthreads();
        passT<1, false, false, false>(smemc, gl + 3 * 8,  nullptr,     nullptr, tid); __syncthreads();
        passT<2, false, false, false>(smemc, gl + 6 * 8,  nullptr,     nullptr, tid); __syncthreads();
        passT<3, false, false, false>(smemc, gl + 9 * 8,  nullptr,     nullptr, tid); __syncthreads();
        passT<4, false, false, false>(smemc, gl + 12 * 8, nullptr,     nullptr, tid); __syncthreads();
    }
    {
        const unsigned* gl = gt + 13 * 8;
        passT<0, false, true,  false>(smemc, gl,          gt + 40 * 8, nullptr, tid); __syncthreads();
        passT<1, false, false, false>(smemc, gl + 3 * 8,  nullptr,     nullptr, tid); __syncthreads();
        passT<2, false, false, false>(smemc, gl + 6 * 8,  nullptr,     nullptr, tid); __syncthreads();
        passT<3, false, false, false>(smemc, gl + 9 * 8,  nullptr,     nullptr, tid); __syncthreads();
        passT<4, false, false, false>(smemc, gl + 12 * 8, nullptr,     nullptr, tid); __syncthreads();
    }
    {
        const unsigned* gl = gt + 26 * 8;
        passT<0, false, true,  false>(smemc, gl,          gt + 41 * 8, nullptr, tid); __syncthreads();
        passT<1, false, false, false>(smemc, gl + 3 * 8,  nullptr,     nullptr, tid); __syncthreads();
        passT<2, false, false, false>(smemc, gl + 6 * 8,  nullptr,     nullptr, tid); __syncthreads();
        passT<3, false, false, false>(smemc, gl + 9 * 8,  nullptr,     nullptr, tid); __syncthreads();
        passT<4, false, false, true >(smemc, gl + 12 * 8, nullptr,     fr,      tid);
    }
}

// ---------------------------------------------------------------------------
// Kernel 2: MFMA GEMM1 v3 — r19's validated 512-thread layout (8 waves =
// 2/SIMD) but B read COALESCED from w1t bf16 (r19's regression was the
// 1KB-strided fp32 B staging, not the thread layout). A and B staging are
// now byte-identical patterns: 1 contiguous uint4 chunk per thread.
// Chunk-swizzle (r9-verified): physical chunk p at row r holds logical
// kb = p ^ ((r>>1)&3). Wave w: rows (w>>1)*32, cols (w&1)*64; 2x4 frags.
// ---------------------------------------------------------------------------
__global__ __launch_bounds__(512) void gemm1_mfma(
    const __hip_bfloat16* __restrict__ A,   // feats (1024, 16384) bf16
    const __hip_bfloat16* __restrict__ B,   // w1t   (256, 16384) bf16
    float* __restrict__ part)               // (16, 1024, 256)
{
    __shared__ char As[8192];
    __shared__ char Bs[8192];
    const int tid  = threadIdx.x;
    const int lane = tid & 63;
    const int wave = tid >> 6;
    const int wm = wave >> 1, wn = wave & 1;
    const int bm = blockIdx.x, bn = blockIdx.y, ks = blockIdx.z;
    const int k0 = ks * 1024;

    // one 16B chunk per thread for each operand
    const int r_  = tid >> 2, kb_ = (tid & 3) ^ ((r_ >> 1) & 3);
    const __hip_bfloat16* Ap = A + (size_t)(bm * 128 + r_) * SDIM + k0 + kb_ * 8;
    const __hip_bfloat16* Bp = B + (size_t)(bn * 128 + r_) * SDIM + k0 + kb_ * 8;

    const int kbx  = lane >> 4;
    const int arow = wm * 32 + (lane & 15);
    const int brow = wn * 64 + (lane & 15);
    const int abase = arow * 64 + ((kbx ^ ((arow >> 1) & 3)) << 4);
    const int bbase = brow * 64 + ((kbx ^ ((brow >> 1) & 3)) << 4);

    f32x4 acc[2][4];
    #pragma unroll
    for (int i = 0; i < 2; ++i)
        #pragma unroll
        for (int j = 0; j < 4; ++j)
            acc[i][j] = (f32x4){0.f, 0.f, 0.f, 0.f};

    uint4 ra = *(const uint4*)Ap;
    uint4 rb = *(const uint4*)Bp;

    for (int kt = 0; kt < 32; ++kt) {
        *(uint4*)(As + tid * 16) = ra;
        *(uint4*)(Bs + tid * 16) = rb;
        __syncthreads();
        if (kt < 31) {   // prefetch next K-step while MFMAs run
            const int d = (kt + 1) * 32;
            ra = *(const uint4*)(Ap + d);
            rb = *(const uint4*)(Bp + d);
        }
        bf16x8 a[2], b[4];
        #pragma unroll
        for (int mi = 0; mi < 2; ++mi) a[mi] = *(const bf16x8*)(As + abase + mi * 1024);
        #pragma unroll
        for (int ni = 0; ni < 4; ++ni) b[ni] = *(const bf16x8*)(Bs + bbase + ni * 1024);
        #pragma unroll
        for (int mi = 0; mi < 2; ++mi)
            #pragma unroll
            for (int ni = 0; ni < 4; ++ni)
                acc[mi][ni] = __builtin_amdgcn_mfma_f32_16x16x32_bf16(a[mi], b[ni], acc[mi][ni], 0, 0, 0);
        __syncthreads();
    }

    float* P = part + ((size_t)ks * NBATCH + bm * 128 + wm * 32) * 256 + bn * 128 + wn * 64;
    const int mrow = (lane >> 4) * 4;
    const int ncol = lane & 15;
    #pragma unroll
    for (int mi = 0; mi < 2; ++mi)
        #pragma unroll
        for (int ni = 0; ni < 4; ++ni) {
            #pragma unroll
            for (int r = 0; r < 4; ++r)
                P[(size_t)(mi * 16 + mrow + r) * 256 + ni * 16 + ncol] = acc[mi][ni][r];
        }
}

// ---------------------------------------------------------------------------
// Kernel 3: reduce split-K partials + bias + relu, then the two small GEMMs.
// ---------------------------------------------------------------------------
__global__ __launch_bounds__(256) void tail_kernel(
    const float* __restrict__ part,  // (16, 1024, 256)
    const float* __restrict__ b1,
    const float* __restrict__ w2,    // (256, 128)
    const float* __restrict__ b2,
    const float* __restrict__ w3,    // (128, 64)
    const float* __restrict__ b3,
    float* __restrict__ out)         // (1024, 64)
{
    __shared__ float h1[256];
    __shared__ float h2[128];
    const int b = blockIdx.x, t = threadIdx.x;

    float s = b1[t];
    #pragma unroll
    for (int sp = 0; sp < KSPLIT; ++sp)
        s += part[((size_t)sp * NBATCH + b) * 256 + t];
    h1[t] = fmaxf(s, 0.f);
    __syncthreads();

    if (t < 128) {
        float acc = b2[t];
        #pragma unroll 4
        for (int k = 0; k < 256; ++k) acc = fmaf(h1[k], w2[k * 128 + t], acc);
        h2[t] = fmaxf(acc, 0.f);
    }
    __syncthreads();

    if (t < 64) {
        float acc = b3[t];
        #pragma unroll 4
        for (int k = 0; k < 128; ++k) acc = fmaf(h2[k], w3[k * 64 + t], acc);
        out[(size_t)b * 64 + t] = acc;
    }
}

// ---------------------------------------------------------------------------
extern "C" void kernel_launch(void* const* d_in, const int* in_sizes, int n_in,
                              void* d_out, int out_size, void* d_ws, size_t ws_size,
                              hipStream_t stream) {
    const float* x   = (const float*)d_in[0];
    const float* ep  = (const float*)d_in[1];
    const float* rp  = (const float*)d_in[2];
    const float* ent = (const float*)d_in[3];
    const float* w1  = (const float*)d_in[4];
    const float* b1  = (const float*)d_in[5];
    const float* w2  = (const float*)d_in[6];
    const float* b2  = (const float*)d_in[7];
    const float* w3  = (const float*)d_in[8];
    const float* b3  = (const float*)d_in[9];
    float* out = (float*)d_out;

    // ws: feats bf16 (32 MiB) | w1t bf16 (8 MiB) | part fp32 (16 MiB) | gtab (1.4 MiB)
    __hip_bfloat16* feats = (__hip_bfloat16*)d_ws;
    __hip_bfloat16* w1t   = feats + (size_t)NBATCH * SDIM;
    float*          part  = (float*)(w1t + (size_t)256 * SDIM);
    unsigned*       gtab  = (unsigned*)(part + (size_t)KSPLIT * NBATCH * 256);

    prep_wtr_kernel<<<NBATCH, 256, 0, stream>>>(x, ep, rp, ent, w1, gtab, w1t);
    sim_kernel<<<NBATCH, 1024, 0, stream>>>(gtab, feats);
    gemm1_mfma<<<dim3(8, 2, KSPLIT), 512, 0, stream>>>(feats, w1t, part);
    tail_kernel<<<NBATCH, 256, 0, stream>>>(part, b1, w2, b2, w3, b3, out);
}

// Round 21
// 156.007 us; speedup vs baseline: 1.0978x; 1.0063x over previous
//
#include <hip/hip_runtime.h>
#include <hip/hip_bf16.h>
#include <cstdint>
#include <cstddef>

#define NQ      14
#define SDIM    16384          // 1 << NQ
#define NGATES  39             // 3 layers * 13 sparse two-qubit chain gates
#define NBATCH  1024
#define KSPLIT  16
#define GENT    42             // 39 chain gates + 3 per-layer U0

typedef short bf16x8 __attribute__((ext_vector_type(8)));
typedef float f32x4  __attribute__((ext_vector_type(4)));
typedef __fp16 half2v __attribute__((ext_vector_type(2)));

// ---------------------------------------------------------------------------
// scalar complex helpers (prep kernel only)
// ---------------------------------------------------------------------------
__device__ __forceinline__ float2 cmul(float2 a, float2 b) {
    return make_float2(fmaf(a.x, b.x, -a.y * b.y), fmaf(a.x, b.y, a.y * b.x));
}
__device__ __forceinline__ void cfma(float2 &o, float2 a, float2 b) {
    o.x = fmaf(a.x, b.x, fmaf(-a.y, b.y, o.x));
    o.y = fmaf(a.x, b.y, fmaf( a.y, b.x, o.y));
}

// ---------------------------------------------------------------------------
// Packed fp16 complex helpers (r16/r18-verified). Amp = one uint (lo=re,
// hi=im). Coefficients bound as SGPR ("s") — wave-uniform, rides the scalar
// file, keeps VGPR demand at the 32-reg clamp with zero spill.
// ---------------------------------------------------------------------------
__device__ __forceinline__ unsigned cmul16(unsigned c, unsigned a) {
    unsigned t, o;
    asm("v_pk_mul_f16 %0, %2, %3 op_sel:[0,0] op_sel_hi:[0,1]\n\t"
        "v_pk_fma_f16 %1, %2, %3, %0 op_sel:[1,1,0] op_sel_hi:[1,0,1] neg_lo:[1,0,0]"
        : "=&v"(t), "=v"(o) : "s"(c), "v"(a));
    return o;
}
__device__ __forceinline__ void cfma16(unsigned &o, unsigned c, unsigned a) {
    unsigned t;
    asm("v_pk_fma_f16 %0, %2, %3, %1 op_sel:[0,0,0] op_sel_hi:[0,1,1]\n\t"
        "v_pk_fma_f16 %1, %2, %3, %0 op_sel:[1,1,0] op_sel_hi:[1,0,1] neg_lo:[1,0,0]"
        : "=&v"(t), "+v"(o) : "s"(c), "v"(a));
}

__device__ void mm2(const float2 A[2][2], const float2 B[2][2], float2 C[2][2]) {
    #pragma unroll
    for (int i = 0; i < 2; ++i)
        #pragma unroll
        for (int j = 0; j < 2; ++j) {
            float2 t = cmul(A[i][0], B[0][j]);
            cfma(t, A[i][1], B[1][j]);
            C[i][j] = t;
        }
}

// U = RZ(g) * RY(b) * RX(a)  (optionally right-multiplied by encoding RY for layer 0)
__device__ void build_u(const float* __restrict__ rp, const float* __restrict__ enc,
                        int l, int q, float2 U[2][2]) {
    const float* p = rp + (l * NQ + q) * 3;
    float ha = 0.5f * p[0], hb = 0.5f * p[1], hg = 0.5f * p[2];
    float cx = cosf(ha), sx = sinf(ha);
    float cy = cosf(hb), sy = sinf(hb);
    float cz = cosf(hg), sz = sinf(hg);
    float2 RX[2][2] = { { make_float2(cx, 0.f), make_float2(0.f, -sx) },
                        { make_float2(0.f, -sx), make_float2(cx, 0.f) } };
    float2 RY[2][2] = { { make_float2(cy, 0.f), make_float2(-sy, 0.f) },
                        { make_float2(sy, 0.f), make_float2(cy, 0.f) } };
    float2 W[2][2];
    mm2(RY, RX, W);
    float2 zl = make_float2(cz, -sz), zh = make_float2(cz, sz);
    float2 V[2][2];
    V[0][0] = cmul(zl, W[0][0]); V[0][1] = cmul(zl, W[0][1]);
    V[1][0] = cmul(zh, W[1][0]); V[1][1] = cmul(zh, W[1][1]);
    if (l == 0) {   // encoding RY applied BEFORE layer-0 rotations -> right-multiply
        float he = 0.5f * enc[q];
        float ce = cosf(he), se = sinf(he);
        float2 RE[2][2] = { { make_float2(ce, 0.f), make_float2(-se, 0.f) },
                            { make_float2(se, 0.f), make_float2(ce, 0.f) } };
        mm2(V, RE, U);
    } else {
        U[0][0] = V[0][0]; U[0][1] = V[0][1];
        U[1][0] = V[1][0]; U[1][1] = V[1][1];
    }
}

__device__ __forceinline__ unsigned pkh(float2 f) {
    half2v h = __builtin_amdgcn_cvt_pkrtz(f.x, f.y);
    return *(unsigned*)&h;
}

// ---------------------------------------------------------------------------
// Kernel 0: per-batch gate-table build (gates only, ~3 µs; the w1 transpose
// is fused into sim_kernel's tail where its 96 MB of HBM traffic hides under
// sim's VALU-bound execution — sim uses only 4.7% of HBM BW).
// gtab[b]: entries 0..38 = chain gates (8 uints); 39..41 = per-layer U(q0).
// ---------------------------------------------------------------------------
__global__ __launch_bounds__(64) void prep_kernel(
    const float* __restrict__ x,     // (1024, 64)
    const float* __restrict__ ep,    // (64, 14)
    const float* __restrict__ rp,    // (3, 14, 3)
    const float* __restrict__ ent,   // (3, 13)
    unsigned* __restrict__ gtab)     // (1024, 42*8)
{
    __shared__ float angles[NQ];
    const int b = blockIdx.x, t = threadIdx.x;

    if (t < NQ) {
        float a = 0.f;
        const float* xr = x + (size_t)b * 64;
        #pragma unroll 8
        for (int k = 0; k < 64; ++k) a = fmaf(xr[k], ep[k * NQ + t], a);
        angles[t] = a;
    }
    __syncthreads();

    unsigned* G0 = gtab + (size_t)b * (GENT * 8);
    if (t < NGATES) {
        int l = t / 13, jj = t - l * 13;     // gate on qubits (jj, jj+1)
        float2 Ut[2][2];
        build_u(rp, angles, l, jj + 1, Ut);
        float th = ent[l * 13 + jj];
        float ct = cosf(th), s = sinf(th);
        unsigned* G = G0 + t * 8;
        G[0] = pkh(Ut[0][0]); G[1] = pkh(Ut[0][1]); G[2] = pkh(Ut[1][0]); G[3] = pkh(Ut[1][1]);
        G[4] = pkh(make_float2(fmaf(ct, Ut[0][0].x, -s * Ut[1][0].y), fmaf(ct, Ut[0][0].y, s * Ut[1][0].x)));
        G[5] = pkh(make_float2(fmaf(ct, Ut[0][1].x, -s * Ut[1][1].y), fmaf(ct, Ut[0][1].y, s * Ut[1][1].x)));
        G[6] = pkh(make_float2(fmaf(ct, Ut[1][0].x, -s * Ut[0][0].y), fmaf(ct, Ut[1][0].y, s * Ut[0][0].x)));
        G[7] = pkh(make_float2(fmaf(ct, Ut[1][1].x, -s * Ut[0][1].y), fmaf(ct, Ut[1][1].y, s * Ut[0][1].x)));
    } else if (t < GENT) {
        int l = t - NGATES;
        float2 U[2][2];
        build_u(rp, angles, l, 0, U);
        unsigned* D = G0 + t * 8;
        D[0] = pkh(U[0][0]); D[1] = pkh(U[0][1]); D[2] = pkh(U[1][0]); D[3] = pkh(U[1][1]);
    }
}

// ---------------------------------------------------------------------------
// Sparse chain-gate on the 4-qubit register window — fp16-packed, SGPR coeffs.
// ---------------------------------------------------------------------------
template<int CP>
__device__ __forceinline__ void gate_sparse8(unsigned v[16], const unsigned* __restrict__ G) {
    {
        unsigned c00 = G[0], c01 = G[1], c10 = G[2], c11 = G[3];
        #pragma unroll
        for (int rr = 0; rr < 4; ++rr) {
            const int base = ((rr >> CP) << (CP + 2)) | (rr & ((1 << CP) - 1));
            const int m0 = base, m2 = base | (2 << CP);
            unsigned a0 = v[m0], a2 = v[m2];
            unsigned o0 = cmul16(c00, a0); cfma16(o0, c01, a2);
            unsigned o2 = cmul16(c10, a0); cfma16(o2, c11, a2);
            v[m0] = o0; v[m2] = o2;
        }
    }
    {
        unsigned c00 = G[4], c01 = G[5], c10 = G[6], c11 = G[7];
        #pragma unroll
        for (int rr = 0; rr < 4; ++rr) {
            const int base = ((rr >> CP) << (CP + 2)) | (rr & ((1 << CP) - 1));
            const int m1 = base | (1 << CP), m3 = base | (3 << CP);
            unsigned a1 = v[m1], a3 = v[m3];
            unsigned o1 = cmul16(c00, a1); cfma16(o1, c01, a3);
            unsigned o3 = cmul16(c10, a1); cfma16(o3, c11, a3);
            v[m1] = o1; v[m3] = o3;
        }
    }
}

// ---------------------------------------------------------------------------
// LDS layout (b32): slot = amp ^ ((amp>>5)&31); bank = slot[4:0]. All five
// mappings give exactly 2 lanes/bank (free) per wave64 b32 access.
// ---------------------------------------------------------------------------
template<int P> __device__ __forceinline__ int pass_i0(int tid) {
    if constexpr (P == 0) return ((tid & 15) << 5) | (tid & 16) | ((tid & 32) << 4) | ((tid & 0x3C0) << 4);
    if constexpr (P == 1) return (tid & 7) | (((tid >> 4) & 1) << 7) | (((tid >> 3) & 1) << 8)
                               | (((tid >> 5) & 1) << 9) | ((tid >> 6) << 10);
    if constexpr (P == 2) return (tid & 63) | ((tid >> 6) << 10);
    if constexpr (P == 3) return (tid & 31) | (((tid >> 6) & 15) << 5) | (((tid >> 5) & 1) << 13);
    if constexpr (P == 4) return (tid & 31) | (((tid >> 6) & 15) << 5) | (((tid >> 5) & 1) << 9);
    return 0;
}
template<int P> __device__ __forceinline__ constexpr int pass_cj(int j) {
    if constexpr (P == 0) return j * 4;
    if constexpr (P == 1) return (((j << 3) | (j >> 2))) * 4;
    if constexpr (P == 2) return (((j << 6) | (j << 1))) * 4;
    if constexpr (P == 3) return (((j << 9) | ((j & 1) << 4))) * 4;
    if constexpr (P == 4) return (j << 10) * 4;
    return 0;
}

template<int P, bool INIT, bool U0F, bool EMIT>
__device__ __forceinline__ void passT(char* __restrict__ smemc,
                                      const unsigned* __restrict__ gb,
                                      const unsigned* __restrict__ u0,
                                      __hip_bfloat16* __restrict__ fr, int tid) {
    const int i0   = pass_i0<P>(tid);
    const int base = (i0 ^ ((i0 >> 5) & 31)) * 4;

    unsigned v[16];
    if (INIT) {
        #pragma unroll
        for (int j = 0; j < 16; ++j) v[j] = 0u;
        if (tid == 0) v[0] = 0x3C00u;       // fp16 (1.0, 0.0)
    } else {
        #pragma unroll
        for (int j = 0; j < 16; ++j)
            v[j] = *(const unsigned*)(smemc + (base ^ pass_cj<P>(j)));
    }

    if (U0F) {
        unsigned u00 = u0[0], u01 = u0[1], u10 = u0[2], u11 = u0[3];
        #pragma unroll
        for (int k = 0; k < 8; ++k) {
            unsigned e = v[2 * k], o = v[2 * k + 1];
            unsigned ne = cmul16(u00, e); cfma16(ne, u01, o);
            unsigned no = cmul16(u10, e); cfma16(no, u11, o);
            v[2 * k] = ne; v[2 * k + 1] = no;
        }
    }

    if (P < 4) {
        gate_sparse8<0>(v, gb);
        gate_sparse8<1>(v, gb + 8);
        gate_sparse8<2>(v, gb + 16);
    } else {
        gate_sparse8<2>(v, gb);
    }

    if (EMIT) {
        #pragma unroll
        for (int j = 0; j < 16; ++j) {
            half2v h = *(half2v*)&v[j];
            float re = (float)h.x, im = (float)h.y;
            fr[i0 + (j << 10)] = __float2bfloat16(fmaf(re, re, im * im));
        }
    } else {
        #pragma unroll
        for (int j = 0; j < 16; ++j)
            *(unsigned*)(smemc + (base ^ pass_cj<P>(j))) = v[j];
    }
}

// ---------------------------------------------------------------------------
// Kernel 1: circuit simulation (r18/r20-verified config) + FUSED w1
// transpose in the tail: after the final EMIT the 64 KB st buffer is dead,
// so block b restages w1 tile (b>>2, b&3) through it (r18-verified pattern,
// 64x65 padded). Its 96 MB of HBM traffic overlaps sim's VALU-bound body
// instead of costing a serial ~15-17 µs prep_wtr stage.
// ---------------------------------------------------------------------------
__global__ __launch_bounds__(1024) __attribute__((amdgpu_waves_per_eu(8, 8)))
void sim_kernel(
    const unsigned* __restrict__ gtab,   // (1024, 42*8) packed fp16 coeffs
    const float* __restrict__ w1,        // (16384, 256) fp32
    __hip_bfloat16* __restrict__ feats,  // (1024, 16384) bf16
    __hip_bfloat16* __restrict__ w1t)    // (256, 16384) bf16
{
    __shared__ unsigned int st[SDIM];      // 65536 B exactly

    char* smemc = (char*)st;
    const int tid = threadIdx.x;
    const int b   = blockIdx.x;

    const unsigned* gt = gtab + (size_t)b * (GENT * 8);
    __hip_bfloat16* fr = feats + (size_t)b * SDIM;

    {
        const unsigned* gl = gt;
        passT<0, true,  true,  false>(smemc, gl,          gt + 39 * 8, nullptr, tid); __syncthreads();
        passT<1, false, false, false>(smemc, gl + 3 * 8,  nullptr,     nullptr, tid); __syncthreads();
        passT<2, false, false, false>(smemc, gl + 6 * 8,  nullptr,     nullptr, tid); __syncthreads();
        passT<3, false, false, false>(smemc, gl + 9 * 8,  nullptr,     nullptr, tid); __syncthreads();
        passT<4, false, false, false>(smemc, gl + 12 * 8, nullptr,     nullptr, tid); __syncthreads();
    }
    {
        const unsigned* gl = gt + 13 * 8;
        passT<0, false, true,  false>(smemc, gl,          gt + 40 * 8, nullptr, tid); __syncthreads();
        passT<1, false, false, false>(smemc, gl + 3 * 8,  nullptr,     nullptr, tid); __syncthreads();
        passT<2, false, false, false>(smemc, gl + 6 * 8,  nullptr,     nullptr, tid); __syncthreads();
        passT<3, false, false, false>(smemc, gl + 9 * 8,  nullptr,     nullptr, tid); __syncthreads();
        passT<4, false, false, false>(smemc, gl + 12 * 8, nullptr,     nullptr, tid); __syncthreads();
    }
    {
        const unsigned* gl = gt + 26 * 8;
        passT<0, false, true,  false>(smemc, gl,          gt + 41 * 8, nullptr, tid); __syncthreads();
        passT<1, false, false, false>(smemc, gl + 3 * 8,  nullptr,     nullptr, tid); __syncthreads();
        passT<2, false, false, false>(smemc, gl + 6 * 8,  nullptr,     nullptr, tid); __syncthreads();
        passT<3, false, false, false>(smemc, gl + 9 * 8,  nullptr,     nullptr, tid); __syncthreads();
        passT<4, false, false, true >(smemc, gl + 12 * 8, nullptr,     fr,      tid);
    }

    // --- fused w1 transpose/convert: tile (b>>2, b&3), staged through st ---
    __syncthreads();                       // all lanes done reading st
    float (*tile)[65] = (float(*)[65])st;  // 64*65*4 = 16.9 KB of the 64 KB
    const int kb = (b >> 2) * 64, nb = (b & 3) * 64;
    #pragma unroll
    for (int i = 0; i < 4; ++i) {
        int idx = tid + i * 1024; int r = idx >> 6, c = idx & 63;
        tile[r][c] = w1[(size_t)(kb + r) * 256 + nb + c];
    }
    __syncthreads();
    #pragma unroll
    for (int i = 0; i < 4; ++i) {
        int idx = tid + i * 1024; int n = idx >> 6, k = idx & 63;
        w1t[(size_t)(nb + n) * SDIM + kb + k] = __float2bfloat16(tile[k][n]);
    }
}

// ---------------------------------------------------------------------------
// Kernel 2: MFMA GEMM1 v3 (r20-verified): 512 threads (8 waves = 2/SIMD),
// A and B staged as identical coalesced uint4 chunks from feats/w1t.
// Chunk-swizzle: physical chunk p at row r holds logical kb = p^((r>>1)&3).
// Wave w: rows (w>>1)*32, cols (w&1)*64; 2x4 frags of 16x16x32.
// ---------------------------------------------------------------------------
__global__ __launch_bounds__(512) void gemm1_mfma(
    const __hip_bfloat16* __restrict__ A,   // feats (1024, 16384) bf16
    const __hip_bfloat16* __restrict__ B,   // w1t   (256, 16384) bf16
    float* __restrict__ part)               // (16, 1024, 256)
{
    __shared__ char As[8192];
    __shared__ char Bs[8192];
    const int tid  = threadIdx.x;
    const int lane = tid & 63;
    const int wave = tid >> 6;
    const int wm = wave >> 1, wn = wave & 1;
    const int bm = blockIdx.x, bn = blockIdx.y, ks = blockIdx.z;
    const int k0 = ks * 1024;

    const int r_  = tid >> 2, kb_ = (tid & 3) ^ ((r_ >> 1) & 3);
    const __hip_bfloat16* Ap = A + (size_t)(bm * 128 + r_) * SDIM + k0 + kb_ * 8;
    const __hip_bfloat16* Bp = B + (size_t)(bn * 128 + r_) * SDIM + k0 + kb_ * 8;

    const int kbx  = lane >> 4;
    const int arow = wm * 32 + (lane & 15);
    const int brow = wn * 64 + (lane & 15);
    const int abase = arow * 64 + ((kbx ^ ((arow >> 1) & 3)) << 4);
    const int bbase = brow * 64 + ((kbx ^ ((brow >> 1) & 3)) << 4);

    f32x4 acc[2][4];
    #pragma unroll
    for (int i = 0; i < 2; ++i)
        #pragma unroll
        for (int j = 0; j < 4; ++j)
            acc[i][j] = (f32x4){0.f, 0.f, 0.f, 0.f};

    uint4 ra = *(const uint4*)Ap;
    uint4 rb = *(const uint4*)Bp;

    for (int kt = 0; kt < 32; ++kt) {
        *(uint4*)(As + tid * 16) = ra;
        *(uint4*)(Bs + tid * 16) = rb;
        __syncthreads();
        if (kt < 31) {   // prefetch next K-step while MFMAs run
            const int d = (kt + 1) * 32;
            ra = *(const uint4*)(Ap + d);
            rb = *(const uint4*)(Bp + d);
        }
        bf16x8 a[2], b[4];
        #pragma unroll
        for (int mi = 0; mi < 2; ++mi) a[mi] = *(const bf16x8*)(As + abase + mi * 1024);
        #pragma unroll
        for (int ni = 0; ni < 4; ++ni) b[ni] = *(const bf16x8*)(Bs + bbase + ni * 1024);
        #pragma unroll
        for (int mi = 0; mi < 2; ++mi)
            #pragma unroll
            for (int ni = 0; ni < 4; ++ni)
                acc[mi][ni] = __builtin_amdgcn_mfma_f32_16x16x32_bf16(a[mi], b[ni], acc[mi][ni], 0, 0, 0);
        __syncthreads();
    }

    float* P = part + ((size_t)ks * NBATCH + bm * 128 + wm * 32) * 256 + bn * 128 + wn * 64;
    const int mrow = (lane >> 4) * 4;
    const int ncol = lane & 15;
    #pragma unroll
    for (int mi = 0; mi < 2; ++mi)
        #pragma unroll
        for (int ni = 0; ni < 4; ++ni) {
            #pragma unroll
            for (int r = 0; r < 4; ++r)
                P[(size_t)(mi * 16 + mrow + r) * 256 + ni * 16 + ncol] = acc[mi][ni][r];
        }
}

// ---------------------------------------------------------------------------
// Kernel 3: reduce split-K partials + bias + relu, then the two small GEMMs.
// ---------------------------------------------------------------------------
__global__ __launch_bounds__(256) void tail_kernel(
    const float* __restrict__ part,  // (16, 1024, 256)
    const float* __restrict__ b1,
    const float* __restrict__ w2,    // (256, 128)
    const float* __restrict__ b2,
    const float* __restrict__ w3,    // (128, 64)
    const float* __restrict__ b3,
    float* __restrict__ out)         // (1024, 64)
{
    __shared__ float h1[256];
    __shared__ float h2[128];
    const int b = blockIdx.x, t = threadIdx.x;

    float s = b1[t];
    #pragma unroll
    for (int sp = 0; sp < KSPLIT; ++sp)
        s += part[((size_t)sp * NBATCH + b) * 256 + t];
    h1[t] = fmaxf(s, 0.f);
    __syncthreads();

    if (t < 128) {
        float acc = b2[t];
        #pragma unroll 4
        for (int k = 0; k < 256; ++k) acc = fmaf(h1[k], w2[k * 128 + t], acc);
        h2[t] = fmaxf(acc, 0.f);
    }
    __syncthreads();

    if (t < 64) {
        float acc = b3[t];
        #pragma unroll 4
        for (int k = 0; k < 128; ++k) acc = fmaf(h2[k], w3[k * 64 + t], acc);
        out[(size_t)b * 64 + t] = acc;
    }
}

// ---------------------------------------------------------------------------
extern "C" void kernel_launch(void* const* d_in, const int* in_sizes, int n_in,
                              void* d_out, int out_size, void* d_ws, size_t ws_size,
                              hipStream_t stream) {
    const float* x   = (const float*)d_in[0];
    const float* ep  = (const float*)d_in[1];
    const float* rp  = (const float*)d_in[2];
    const float* ent = (const float*)d_in[3];
    const float* w1  = (const float*)d_in[4];
    const float* b1  = (const float*)d_in[5];
    const float* w2  = (const float*)d_in[6];
    const float* b2  = (const float*)d_in[7];
    const float* w3  = (const float*)d_in[8];
    const float* b3  = (const float*)d_in[9];
    float* out = (float*)d_out;

    // ws: feats bf16 (32 MiB) | w1t bf16 (8 MiB) | part fp32 (16 MiB) | gtab (1.4 MiB)
    __hip_bfloat16* feats = (__hip_bfloat16*)d_ws;
    __hip_bfloat16* w1t   = feats + (size_t)NBATCH * SDIM;
    float*          part  = (float*)(w1t + (size_t)256 * SDIM);
    unsigned*       gtab  = (unsigned*)(part + (size_t)KSPLIT * NBATCH * 256);

    prep_kernel<<<NBATCH, 64, 0, stream>>>(x, ep, rp, ent, gtab);
    sim_kernel<<<NBATCH, 1024, 0, stream>>>(gtab, w1, feats, w1t);
    gemm1_mfma<<<dim3(8, 2, KSPLIT), 512, 0, stream>>>(feats, w1t, part);
    tail_kernel<<<NBATCH, 256, 0, stream>>>(part, b1, w2, b2, w3, b3, out);
}